// Round 20
// baseline (418.433 us; speedup 1.0000x reference)
//
#include <hip/hip_runtime.h>
#include <hip/hip_bf16.h>

#define N_TOK 131072
#define DIM   512
#define HID   512
#define NEXP  10

using bf16x8 = __attribute__((ext_vector_type(8))) short;
using f32x4  = __attribute__((ext_vector_type(4))) float;

__device__ __forceinline__ short f2bf(float f) {
    union { float f; unsigned u; } v; v.f = f;
    unsigned u = v.u;
    return (short)((u + 0x7FFFu + ((u >> 16) & 1u)) >> 16);   // RNE
}

#define GLOAD16(g, l) __builtin_amdgcn_global_load_lds( \
    (const __attribute__((address_space(1))) void*)(g),  \
    (__attribute__((address_space(3))) void*)(l), 16, 0, 0)

// ---------------- router: logits = x @ Wr^T + br, argmax; also emits xb = bf16(x) ----------------
__global__ __launch_bounds__(256) void router_kernel(
    const float* __restrict__ x, const float* __restrict__ Wr,
    const float* __restrict__ br, int* __restrict__ eid,
    float* __restrict__ ids_out, int* __restrict__ counts,
    short* __restrict__ xb)
{
    __shared__ float wr[NEXP][DIM];
    __shared__ int lcnt[NEXP];
    int tid = threadIdx.x;
    for (int i = tid; i < NEXP * DIM / 4; i += 256)
        ((float4*)wr)[i] = ((const float4*)Wr)[i];
    if (tid < NEXP) lcnt[tid] = 0;
    __syncthreads();

    int lane  = tid & 63;
    int wave  = tid >> 6;
    int gwave = blockIdx.x * 4 + wave;
    int nwav  = gridDim.x * 4;

    for (int t = gwave; t < N_TOK; t += nwav) {
        const float4* xr = (const float4*)(x + (size_t)t * DIM);
        float4 v0 = xr[lane * 2], v1 = xr[lane * 2 + 1];
        float xf[8] = {v0.x, v0.y, v0.z, v0.w, v1.x, v1.y, v1.z, v1.w};
        bf16x8 p;
        #pragma unroll
        for (int j = 0; j < 8; ++j) p[j] = f2bf(xf[j]);
        *(bf16x8*)(xb + (size_t)t * DIM + lane * 8) = p;

        float dot[NEXP];
        #pragma unroll
        for (int e = 0; e < NEXP; ++e) {
            const float* wv = &wr[e][lane * 8];
            float s = 0.f;
            #pragma unroll
            for (int j = 0; j < 8; ++j) s = fmaf(xf[j], wv[j], s);
            dot[e] = s;
        }
        #pragma unroll
        for (int off = 32; off > 0; off >>= 1) {
            #pragma unroll
            for (int e = 0; e < NEXP; ++e) dot[e] += __shfl_xor(dot[e], off, 64);
        }
        if (lane == 0) {
            int best = 0; float bv = dot[0] + br[0];
            #pragma unroll
            for (int e = 1; e < NEXP; ++e) {
                float v = dot[e] + br[e];
                if (v > bv) { bv = v; best = e; }
            }
            eid[t] = best;
            ids_out[t] = (float)best;
            atomicAdd(&lcnt[best], 1);
        }
    }
    __syncthreads();
    if (tid < NEXP) atomicAdd(&counts[tid], lcnt[tid]);
}

// ---------------- bucket scatter: perm[offset[e] + pos] = token ----------------
__global__ __launch_bounds__(256) void scatter_kernel(
    const int* __restrict__ eid, const int* __restrict__ offsets,
    int* __restrict__ cursors, int* __restrict__ perm)
{
    __shared__ int lcnt[NEXP], lbase[NEXP];
    int tid = threadIdx.x;
    if (tid < NEXP) lcnt[tid] = 0;
    __syncthreads();
    int t = blockIdx.x * 256 + tid;
    int e = 0, lpos = 0;
    if (t < N_TOK) {
        e = eid[t];
        lpos = atomicAdd(&lcnt[e], 1);
    }
    __syncthreads();
    if (tid < NEXP) lbase[tid] = atomicAdd(&cursors[tid], lcnt[tid]);
    __syncthreads();
    if (t < N_TOK) perm[offsets[e] + lbase[e] + lpos] = t;
}

// ---- transpose-convert weights -> k-blocked bf16 [16][512 n][32 k]; block 0 also does offsets ----
__global__ __launch_bounds__(256) void wconvert_kernel(
    const float* __restrict__ W1, const float* __restrict__ W2,
    short* __restrict__ W1b, short* __restrict__ W2b,
    const int* __restrict__ counts, int* __restrict__ offsets, int* __restrict__ toff)
{
    if (blockIdx.x == 0 && blockIdx.y == 0 && blockIdx.z == 0 && threadIdx.x == 0) {
        int acc = 0, ta = 0;
        for (int e = 0; e < NEXP; ++e) {
            offsets[e] = acc; toff[e] = ta;
            acc += counts[e]; ta += (counts[e] + 127) >> 7;
        }
        offsets[NEXP] = acc; toff[NEXP] = ta;
    }
    int mat = blockIdx.z;
    const float* src = (mat < NEXP) ? W1 + (size_t)mat * 512 * 512
                                    : W2 + (size_t)(mat - NEXP) * 512 * 512;
    short* dst = (mat < NEXP) ? W1b + (size_t)mat * 512 * 512
                              : W2b + (size_t)(mat - NEXP) * 512 * 512;
    __shared__ float tile[64][65];
    int r0 = blockIdx.y * 64, c0 = blockIdx.x * 64;   // r0 = k base, c0 = n base
    int tid = threadIdx.x;
    int tr = tid >> 4, tc4 = (tid & 15) * 4;
    #pragma unroll
    for (int i = 0; i < 4; ++i) {
        float4 v = *(const float4*)(src + (size_t)(r0 + i * 16 + tr) * 512 + c0 + tc4);
        tile[i * 16 + tr][tc4 + 0] = v.x; tile[i * 16 + tr][tc4 + 1] = v.y;
        tile[i * 16 + tr][tc4 + 2] = v.z; tile[i * 16 + tr][tc4 + 3] = v.w;
    }
    __syncthreads();
    int s   = (r0 + tc4) >> 5;     // 32k-block
    int kin = (r0 + tc4) & 31;
    #pragma unroll
    for (int i = 0; i < 4; ++i) {
        int cc = i * 16 + tr;      // n within tile
        ushort4 o;
        o.x = (ushort)f2bf(tile[tc4 + 0][cc]); o.y = (ushort)f2bf(tile[tc4 + 1][cc]);
        o.z = (ushort)f2bf(tile[tc4 + 2][cc]); o.w = (ushort)f2bf(tile[tc4 + 3][cc]);
        *(ushort4*)(dst + (size_t)s * 16384 + (size_t)(c0 + cc) * 32 + kin) = o;
    }
}

// ---------------- MFMA expert GEMM: 128 x 256 tile, K=512, 8 waves, DEPTH-3 prefetch ----------------
// R11 geometry + swizzle, but 4 LDS buffers, stage(t+3), counted vmcnt(6): each stage gets
// ~3 compute-steps of latency cover (T4 formula: N = 3 loads/stage x 2 stages in flight).
// Ledger: prologue stage(0,1,2), vmcnt(6) [stage0 done]. Loop t: stage(t+3,(t+3)&3); comp(t&3);
//   wait t<=12 -> vmcnt(6) [stage(t+1) done], t=13 -> vmcnt(3), t=14 -> vmcnt(0); barrier.
// WAR: stage(t+3) overwrites buf((t-1)&3); its readers (comp(t-1)) finished before the barrier
// that ended step t-1, which precedes this issue. RAW: vmcnt chain above.
// LDS 16B-slot swizzle q^((row>>1)&3) (R7-verified conflicts->0), source-side + read-side.
// LAYER==1: A = gathered xb rows, out = relu(.+b1) -> h   LAYER==2: A = h, out = .+b2 -> out[tok]
template<int LAYER>
__global__ __launch_bounds__(512, 2) void expert_gemm(
    const short* __restrict__ xb, const short* __restrict__ hA,
    const short* __restrict__ WT, const float* __restrict__ bias,
    const int* __restrict__ offsets, const int* __restrict__ toff,
    const int* __restrict__ perm,
    short* __restrict__ hOut, float* __restrict__ out)
{
    int g = blockIdx.x;
    if (g >= toff[NEXP]) return;
    int e = 0;
    #pragma unroll
    for (int k = 1; k < NEXP; ++k) e += (g >= toff[k]);
    int beg = offsets[e], cnt = offsets[e + 1] - beg;
    int m0 = (g - toff[e]) * 128;
    int nb = blockIdx.y * 256;

    __shared__ int toks[128];
    __shared__ short Ab[4][128 * 32];   // 8 KB per buf, [row][32k] 16B-slot-swizzled
    __shared__ short Bb[4][256 * 32];   // 16 KB per buf

    int tid = threadIdx.x, lane = tid & 63, w = tid >> 6;
    if (tid < 128) toks[tid] = perm[beg + min(m0 + tid, cnt - 1)];
    __syncthreads();

    // ---- staging addresses (source pre-swizzled; LDS dest linear) ----
    const short* WTe = WT + (size_t)e * 512 * 512;
    int srow = w * 16 + (lane >> 2);       // 0..127 (A row / B row0; B row1 = srow+128)
    int kqp  = lane & 3;                   // physical 16B slot
    int ql   = kqp ^ ((srow >> 1) & 3);    // logical k-quarter stored at this slot
    const short* aS;                       // ((srow+128)>>1)&3 == (srow>>1)&3 -> same ql for B row1
    if (LAYER == 1) aS = xb + (size_t)toks[srow] * DIM + ql * 8;
    else            aS = hA + (size_t)(beg + min(m0 + srow, cnt - 1)) * HID + ql * 8;
    const short* bS = WTe + (size_t)(nb + srow) * 32 + ql * 8;   // + t*16384; +128 rows = +4096

    auto stage = [&](int t, int b) {       // 3 gloads/thread, linear LDS dest
        GLOAD16(bS + t * 16384,        (char*)&Bb[b][0] + w * 1024);
        GLOAD16(bS + t * 16384 + 4096, (char*)&Bb[b][0] + 8192 + w * 1024);
        GLOAD16(aS + t * 32,           (char*)&Ab[b][0] + w * 1024);
    };

    // ---- fragment read offsets (swizzled, bytes within buffer) ----
    int wr = w >> 2, wc = w & 3, lrow = lane & 15, kq = lane >> 4;
    int offA[4], offB[4];
    #pragma unroll
    for (int i = 0; i < 4; ++i) {
        int r = wr * 64 + i * 16 + lrow;
        offA[i] = r * 64 + (kq ^ ((r >> 1) & 3)) * 16;
    }
    #pragma unroll
    for (int j = 0; j < 4; ++j) {
        int r = wc * 64 + j * 16 + lrow;
        offB[j] = r * 64 + (kq ^ ((r >> 1) & 3)) * 16;
    }

    f32x4 acc[4][4];
    #pragma unroll
    for (int i = 0; i < 4; ++i)
        #pragma unroll
        for (int j = 0; j < 4; ++j) acc[i][j] = (f32x4){0.f, 0.f, 0.f, 0.f};

    auto comp = [&](int b) {
        bf16x8 af[4], bv[4];
        #pragma unroll
        for (int i = 0; i < 4; ++i) af[i] = *(const bf16x8*)((char*)&Ab[b][0] + offA[i]);
        #pragma unroll
        for (int j = 0; j < 4; ++j) bv[j] = *(const bf16x8*)((char*)&Bb[b][0] + offB[j]);
        __builtin_amdgcn_s_setprio(1);
        #pragma unroll
        for (int i = 0; i < 4; ++i)
            #pragma unroll
            for (int j = 0; j < 4; ++j)
                acc[i][j] = __builtin_amdgcn_mfma_f32_16x16x32_bf16(af[i], bv[j], acc[i][j], 0, 0, 0);
        __builtin_amdgcn_s_setprio(0);
    };

    // ---- prologue: fill bufs 0..2 (depth-3), wait for buf0 ----
    stage(0, 0);
    stage(1, 1);
    stage(2, 2);
    asm volatile("s_waitcnt vmcnt(6)" ::: "memory");   // stage(0) complete
    __builtin_amdgcn_s_barrier();

    // ---- main loop: 16 K-steps, depth-3 counted ledger ----
    #pragma unroll
    for (int t = 0; t < 16; ++t) {
        if (t + 3 < 16) stage(t + 3, (t + 3) & 3);
        comp(t & 3);
        if (t == 15) break;
        if (t <= 12)      asm volatile("s_waitcnt vmcnt(6)" ::: "memory");  // stage(t+1) done
        else if (t == 13) asm volatile("s_waitcnt vmcnt(3)" ::: "memory");  // stage(14) done
        else              asm volatile("s_waitcnt vmcnt(0)" ::: "memory");  // stage(15) done
        __builtin_amdgcn_s_barrier();
    }

    // ---- epilogue (R11 verbatim) ----
    const float* be = bias + (size_t)e * 512;
    int colb = nb + wc * 64 + lrow;
    float bvv[4];
    #pragma unroll
    for (int j = 0; j < 4; ++j) bvv[j] = be[colb + j * 16];

    #pragma unroll
    for (int i = 0; i < 4; ++i) {
        #pragma unroll
        for (int q = 0; q < 4; ++q) {
            int rr = wr * 64 + i * 16 + kq * 4 + q;
            if (m0 + rr < cnt) {
                if (LAYER == 1) {
                    short* hp = hOut + (size_t)(beg + m0 + rr) * HID + colb;
                    #pragma unroll
                    for (int j = 0; j < 4; ++j) {
                        float v = acc[i][j][q] + bvv[j];
                        hp[j * 16] = f2bf(v > 0.f ? v : 0.f);
                    }
                } else {
                    float* op = out + (size_t)toks[rr] * HID + colb;
                    #pragma unroll
                    for (int j = 0; j < 4; ++j)
                        op[j * 16] = acc[i][j][q] + bvv[j];
                }
            }
        }
    }
}

extern "C" void kernel_launch(void* const* d_in, const int* in_sizes, int n_in,
                              void* d_out, int out_size, void* d_ws, size_t ws_size,
                              hipStream_t stream)
{
    const float* x  = (const float*)d_in[0];
    const float* Wr = (const float*)d_in[1];
    const float* br = (const float*)d_in[2];
    const float* W1 = (const float*)d_in[3];
    const float* b1 = (const float*)d_in[4];
    const float* W2 = (const float*)d_in[5];
    const float* b2 = (const float*)d_in[6];

    float* out     = (float*)d_out;
    float* ids_out = out + (size_t)N_TOK * HID;

    char* ws     = (char*)d_ws;
    int* counts  = (int*)ws;            // 16 ints
    int* offsets = counts + 16;         // 11 used
    int* toff    = counts + 32;         // 11 used
    int* cursors = counts + 48;         // 16
    int* eid     = (int*)(ws + 1024);
    int* perm    = eid + N_TOK;
    short* W1b   = (short*)(ws + 1024 + (size_t)2 * N_TOK * 4);
    short* W2b   = W1b + (size_t)NEXP * 512 * 512;
    short* h     = W2b + (size_t)NEXP * 512 * 512;
    short* xb    = h   + (size_t)N_TOK * HID;

    (void)hipMemsetAsync(d_ws, 0, 1024, stream);
    router_kernel<<<2048, 256, 0, stream>>>(x, Wr, br, eid, ids_out, counts, xb);
    wconvert_kernel<<<dim3(8, 8, 2 * NEXP), 256, 0, stream>>>(W1, W2, W1b, W2b,
                                                              counts, offsets, toff);
    scatter_kernel<<<512, 256, 0, stream>>>(eid, offsets, cursors, perm);

    int ntiles = (N_TOK + 127) / 128 + NEXP;   // upper bound on 128-row tiles
    expert_gemm<1><<<dim3(ntiles, 2), 512, 0, stream>>>(xb, nullptr, W1b, b1, offsets, toff, perm, h, nullptr);
    expert_gemm<2><<<dim3(ntiles, 2), 512, 0, stream>>>(nullptr, h, W2b, b2, offsets, toff, perm, nullptr, out);
}

// Round 21
// 354.441 us; speedup vs baseline: 1.1805x; 1.1805x over previous
//
#include <hip/hip_runtime.h>
#include <hip/hip_bf16.h>

#define N_TOK 131072
#define DIM   512
#define HID   512
#define NEXP  10

using bf16x8 = __attribute__((ext_vector_type(8))) short;
using f32x4  = __attribute__((ext_vector_type(4))) float;

__device__ __forceinline__ short f2bf(float f) {
    union { float f; unsigned u; } v; v.f = f;
    unsigned u = v.u;
    return (short)((u + 0x7FFFu + ((u >> 16) & 1u)) >> 16);   // RNE
}

#define GLOAD16(g, l) __builtin_amdgcn_global_load_lds( \
    (const __attribute__((address_space(1))) void*)(g),  \
    (__attribute__((address_space(3))) void*)(l), 16, 0, 0)

// ---------------- router: logits = x @ Wr^T + br, argmax; also emits xb = bf16(x) ----------------
__global__ __launch_bounds__(256) void router_kernel(
    const float* __restrict__ x, const float* __restrict__ Wr,
    const float* __restrict__ br, int* __restrict__ eid,
    float* __restrict__ ids_out, int* __restrict__ counts,
    short* __restrict__ xb)
{
    __shared__ float wr[NEXP][DIM];
    __shared__ int lcnt[NEXP];
    int tid = threadIdx.x;
    for (int i = tid; i < NEXP * DIM / 4; i += 256)
        ((float4*)wr)[i] = ((const float4*)Wr)[i];
    if (tid < NEXP) lcnt[tid] = 0;
    __syncthreads();

    int lane  = tid & 63;
    int wave  = tid >> 6;
    int gwave = blockIdx.x * 4 + wave;
    int nwav  = gridDim.x * 4;

    for (int t = gwave; t < N_TOK; t += nwav) {
        const float4* xr = (const float4*)(x + (size_t)t * DIM);
        float4 v0 = xr[lane * 2], v1 = xr[lane * 2 + 1];
        float xf[8] = {v0.x, v0.y, v0.z, v0.w, v1.x, v1.y, v1.z, v1.w};
        bf16x8 p;
        #pragma unroll
        for (int j = 0; j < 8; ++j) p[j] = f2bf(xf[j]);
        *(bf16x8*)(xb + (size_t)t * DIM + lane * 8) = p;

        float dot[NEXP];
        #pragma unroll
        for (int e = 0; e < NEXP; ++e) {
            const float* wv = &wr[e][lane * 8];
            float s = 0.f;
            #pragma unroll
            for (int j = 0; j < 8; ++j) s = fmaf(xf[j], wv[j], s);
            dot[e] = s;
        }
        #pragma unroll
        for (int off = 32; off > 0; off >>= 1) {
            #pragma unroll
            for (int e = 0; e < NEXP; ++e) dot[e] += __shfl_xor(dot[e], off, 64);
        }
        if (lane == 0) {
            int best = 0; float bv = dot[0] + br[0];
            #pragma unroll
            for (int e = 1; e < NEXP; ++e) {
                float v = dot[e] + br[e];
                if (v > bv) { bv = v; best = e; }
            }
            eid[t] = best;
            ids_out[t] = (float)best;
            atomicAdd(&lcnt[best], 1);
        }
    }
    __syncthreads();
    if (tid < NEXP) atomicAdd(&counts[tid], lcnt[tid]);
}

// ---------------- bucket scatter: perm[offset[e] + pos] = token ----------------
__global__ __launch_bounds__(256) void scatter_kernel(
    const int* __restrict__ eid, const int* __restrict__ offsets,
    int* __restrict__ cursors, int* __restrict__ perm)
{
    __shared__ int lcnt[NEXP], lbase[NEXP];
    int tid = threadIdx.x;
    if (tid < NEXP) lcnt[tid] = 0;
    __syncthreads();
    int t = blockIdx.x * 256 + tid;
    int e = 0, lpos = 0;
    if (t < N_TOK) {
        e = eid[t];
        lpos = atomicAdd(&lcnt[e], 1);
    }
    __syncthreads();
    if (tid < NEXP) lbase[tid] = atomicAdd(&cursors[tid], lcnt[tid]);
    __syncthreads();
    if (t < N_TOK) perm[offsets[e] + lbase[e] + lpos] = t;
}

// ---- transpose-convert weights -> k-blocked bf16 [16][512 n][32 k]; block 0 also does offsets ----
// (counts is final: router completes before this kernel in stream order)
__global__ __launch_bounds__(256) void wconvert_kernel(
    const float* __restrict__ W1, const float* __restrict__ W2,
    short* __restrict__ W1b, short* __restrict__ W2b,
    const int* __restrict__ counts, int* __restrict__ offsets, int* __restrict__ toff)
{
    if (blockIdx.x == 0 && blockIdx.y == 0 && blockIdx.z == 0 && threadIdx.x == 0) {
        int acc = 0, ta = 0;
        for (int e = 0; e < NEXP; ++e) {
            offsets[e] = acc; toff[e] = ta;
            acc += counts[e]; ta += (counts[e] + 63) >> 6;
        }
        offsets[NEXP] = acc; toff[NEXP] = ta;
    }
    int mat = blockIdx.z;
    const float* src = (mat < NEXP) ? W1 + (size_t)mat * 512 * 512
                                    : W2 + (size_t)(mat - NEXP) * 512 * 512;
    short* dst = (mat < NEXP) ? W1b + (size_t)mat * 512 * 512
                              : W2b + (size_t)(mat - NEXP) * 512 * 512;
    __shared__ float tile[64][65];
    int r0 = blockIdx.y * 64, c0 = blockIdx.x * 64;   // r0 = k base, c0 = n base
    int tid = threadIdx.x;
    int tr = tid >> 4, tc4 = (tid & 15) * 4;
    #pragma unroll
    for (int i = 0; i < 4; ++i) {
        float4 v = *(const float4*)(src + (size_t)(r0 + i * 16 + tr) * 512 + c0 + tc4);
        tile[i * 16 + tr][tc4 + 0] = v.x; tile[i * 16 + tr][tc4 + 1] = v.y;
        tile[i * 16 + tr][tc4 + 2] = v.z; tile[i * 16 + tr][tc4 + 3] = v.w;
    }
    __syncthreads();
    int s   = (r0 + tc4) >> 5;     // 32k-block
    int kin = (r0 + tc4) & 31;
    #pragma unroll
    for (int i = 0; i < 4; ++i) {
        int cc = i * 16 + tr;      // n within tile
        ushort4 o;
        o.x = (ushort)f2bf(tile[tc4 + 0][cc]); o.y = (ushort)f2bf(tile[tc4 + 1][cc]);
        o.z = (ushort)f2bf(tile[tc4 + 2][cc]); o.w = (ushort)f2bf(tile[tc4 + 3][cc]);
        *(ushort4*)(dst + (size_t)s * 16384 + (size_t)(c0 + cc) * 32 + kin) = o;
    }
}

// ---------------- FUSED expert FFN (R17/R19-proven) + two ledger-safe prologue overlaps ----------------
// L1 (16 steps): h = relu(xb[toks] . W1 + b1) -> Hb (64 KB LDS, slot^(row&7) swizzle, 1KB rows)
// L2 (16 steps): out = Hb . W2 + b2 -> f32 scatter. A-frags from Hb (no staging).
// Overlap tweaks (R20->21): (1) W1-B0 staged BEFORE toks sync (no toks dep);
// (2) W2-B0 staged BEFORE the h-epilogue (pipeline fully drained there; BBUF(0)'s last reader
// passed the t=14 barrier). Ledger re-verified: manual vmcnt(4) retires {perm loads,B0,A0},
// leaving exactly B1(4) in flight, same invariant as R17.
__global__ __launch_bounds__(512, 2) void expert_fused(
    const short* __restrict__ xb, const short* __restrict__ W1,
    const short* __restrict__ W2, const float* __restrict__ b1,
    const float* __restrict__ b2,
    const int* __restrict__ offsets, const int* __restrict__ toff,
    const int* __restrict__ perm, float* __restrict__ out)
{
    // bijective XCD swizzle (m204)
    int nwg = gridDim.x, orig = blockIdx.x;
    int q8 = nwg >> 3, r8 = nwg & 7, xcd = orig & 7;
    int g = (xcd < r8 ? xcd * (q8 + 1) : r8 * (q8 + 1) + (xcd - r8) * q8) + (orig >> 3);
    if (g >= toff[NEXP]) return;
    int e = 0;
    #pragma unroll
    for (int k = 1; k < NEXP; ++k) e += (g >= toff[k]);
    int beg = offsets[e], cnt = offsets[e + 1] - beg;
    int m0 = (g - toff[e]) * 64;

    // LDS: A pair-bufs [0,16K) ; B dbuf [16K,80K) ; Hb [80K,144K) ; toks @144K
    __shared__ char SMEM[147712];
    #define ABUF(b) (SMEM + (b) * 8192)
    #define BBUF(b) (SMEM + 16384 + (b) * 32768)
    #define HBUF    (SMEM + 81920)

    int tid = threadIdx.x, lane = tid & 63, w = tid >> 6;
    int* toks = (int*)(SMEM + 147456);

    const short* W1e = W1 + (size_t)e * 262144;
    const short* W2e = W2 + (size_t)e * 262144;

    // ---- B staging offsets (NO toks dependency) ----
    int boff[4];
    #pragma unroll
    for (int i = 0; i < 4; ++i) {
        int sid = tid + i * 512, c = sid >> 2, qq = sid & 3;
        boff[i] = c * 32 + (qq ^ ((c >> 1) & 3)) * 8;  // shorts; + t*16384
    }

    // toks fill (perm load retires before staging waits matter)
    if (tid < 64) toks[tid] = perm[beg + min(m0 + tid, cnt - 1)];

    // ---- OVERLAP (1): W1-B0 staged before the toks sync ----
    #pragma unroll
    for (int i_ = 0; i_ < 4; ++i_) GLOAD16(W1e + boff[i_], BBUF(0) + tid * 16 + i_ * 8192);

    __syncthreads();                                   // toks visible

    // ---- A staging address (needs toks) ----
    int arow = tid >> 3, asl = tid & 7;
    int aql  = asl ^ (arow & 7);                       // logical 8-slot within 64-k pair
    const short* aS = xb + (size_t)toks[arow] * DIM + aql * 8;   // + pair*64

    GLOAD16(aS, ABUF(0) + tid * 16);                   // A0
    #pragma unroll
    for (int i_ = 0; i_ < 4; ++i_) GLOAD16(W1e + 16384 + boff[i_], BBUF(1) + tid * 16 + i_ * 8192);

    // ---- fragment read constants ----
    int wr = w >> 2, wc = w & 3, lrow = lane & 15, kq = lane >> 4;
    int rA[2];
    #pragma unroll
    for (int i = 0; i < 2; ++i) rA[i] = wr * 32 + i * 16 + lrow;
    int offB[8];
    #pragma unroll
    for (int j = 0; j < 8; ++j) {
        int c = wc * 128 + j * 16 + lrow;
        offB[j] = c * 64 + ((kq ^ ((c >> 1) & 3)) << 4);
    }

    f32x4 acc[2][8];
    #pragma unroll
    for (int i = 0; i < 2; ++i)
        #pragma unroll
        for (int j = 0; j < 8; ++j) acc[i][j] = (f32x4){0.f, 0.f, 0.f, 0.f};

    asm volatile("s_waitcnt vmcnt(4)" ::: "memory");   // B0 + A0 resident; B1 in flight
    __builtin_amdgcn_s_barrier();

    // ================= L1: h = relu(xb.W1 + b1) =================
    #pragma unroll
    for (int t = 0; t < 16; ++t) {
        // comp(t): B from BBUF(t&1), A from ABUF((t>>1)&1) at k-half (t&1)
        {
            bf16x8 af[2], bv[8];
            #pragma unroll
            for (int j = 0; j < 8; ++j) bv[j] = *(const bf16x8*)(BBUF(t & 1) + offB[j]);
            #pragma unroll
            for (int i = 0; i < 2; ++i) {
                int sl = (((t & 1) * 4 + kq) ^ (rA[i] & 7));
                af[i] = *(const bf16x8*)(ABUF((t >> 1) & 1) + rA[i] * 128 + sl * 16);
            }
            __builtin_amdgcn_s_setprio(1);
            #pragma unroll
            for (int i = 0; i < 2; ++i)
                #pragma unroll
                for (int j = 0; j < 8; ++j)
                    acc[i][j] = __builtin_amdgcn_mfma_f32_16x16x32_bf16(af[i], bv[j], acc[i][j], 0, 0, 0);
            __builtin_amdgcn_s_setprio(0);
        }
        if (t == 15) break;
        __builtin_amdgcn_s_barrier();                  // barrier A: buf t&1 reads done
        asm volatile("" ::: "memory");
        if (t + 2 < 16) {
            #pragma unroll
            for (int i_ = 0; i_ < 4; ++i_)
                GLOAD16(W1e + (t + 2) * 16384 + boff[i_], BBUF(t & 1) + tid * 16 + i_ * 8192);
            if ((t & 1) == 0) {
                GLOAD16(aS + (t / 2 + 1) * 64, ABUF((t / 2 + 1) & 1) + tid * 16);
                asm volatile("s_waitcnt vmcnt(5)" ::: "memory");   // step t+1 data resident
            } else {
                asm volatile("s_waitcnt vmcnt(4)" ::: "memory");
            }
        } else {
            asm volatile("s_waitcnt vmcnt(0)" ::: "memory");       // drain B(15)
        }
        __builtin_amdgcn_s_barrier();                  // barrier B: buf (t+1)&1 ready
    }

    // ---- OVERLAP (2): stage W2-B0 into BBUF(0) BEFORE h-epilogue ----
    // Safe: all L1 stages drained (vmcnt(0) at t=14 tail); BBUF(0)'s last reader (comp t=14)
    // passed the barrier ending step 14. comp(15) reads only BBUF(1).
    {
        #pragma unroll
        for (int i_ = 0; i_ < 4; ++i_) GLOAD16(W2e + boff[i_], BBUF(0) + tid * 16 + i_ * 8192);
    }

    // ---- h epilogue: bias + relu -> Hb (swizzled), then reset acc ----
    {
        const float* b1e = b1 + (size_t)e * 512;
        float bv1[8];
        #pragma unroll
        for (int j = 0; j < 8; ++j) bv1[j] = b1e[wc * 128 + j * 16 + lrow];
        #pragma unroll
        for (int i = 0; i < 2; ++i)
            #pragma unroll
            for (int q = 0; q < 4; ++q) {
                int row = wr * 32 + i * 16 + kq * 4 + q;
                #pragma unroll
                for (int j = 0; j < 8; ++j) {
                    int col = wc * 128 + j * 16 + lrow;
                    float v = acc[i][j][q] + bv1[j];
                    v = v > 0.f ? v : 0.f;
                    *(short*)(HBUF + row * 1024 + (((col >> 3) ^ (row & 7)) << 4) + (col & 7) * 2) = f2bf(v);
                }
            }
    }
    __syncthreads();
    #pragma unroll
    for (int i = 0; i < 2; ++i)
        #pragma unroll
        for (int j = 0; j < 8; ++j) acc[i][j] = (f32x4){0.f, 0.f, 0.f, 0.f};

    // ================= L2: out = Hb . W2 + b2 =================
    {
        #pragma unroll
        for (int i_ = 0; i_ < 4; ++i_) GLOAD16(W2e + 16384 + boff[i_], BBUF(1) + tid * 16 + i_ * 8192);
    }
    asm volatile("s_waitcnt vmcnt(4)" ::: "memory");   // W2-B0 resident; W2-B1 in flight
    __builtin_amdgcn_s_barrier();

    #pragma unroll
    for (int t = 0; t < 16; ++t) {
        {
            bf16x8 af[2], bv[8];
            #pragma unroll
            for (int j = 0; j < 8; ++j) bv[j] = *(const bf16x8*)(BBUF(t & 1) + offB[j]);
            #pragma unroll
            for (int i = 0; i < 2; ++i) {
                int s = (t * 4 + kq) ^ (rA[i] & 7);
                af[i] = *(const bf16x8*)(HBUF + rA[i] * 1024 + (s << 4));
            }
            __builtin_amdgcn_s_setprio(1);
            #pragma unroll
            for (int i = 0; i < 2; ++i)
                #pragma unroll
                for (int j = 0; j < 8; ++j)
                    acc[i][j] = __builtin_amdgcn_mfma_f32_16x16x32_bf16(af[i], bv[j], acc[i][j], 0, 0, 0);
            __builtin_amdgcn_s_setprio(0);
        }
        if (t == 15) break;
        __builtin_amdgcn_s_barrier();
        asm volatile("" ::: "memory");
        if (t + 2 < 16) {
            #pragma unroll
            for (int i_ = 0; i_ < 4; ++i_)
                GLOAD16(W2e + (t + 2) * 16384 + boff[i_], BBUF(t & 1) + tid * 16 + i_ * 8192);
            asm volatile("s_waitcnt vmcnt(4)" ::: "memory");
        } else {
            asm volatile("s_waitcnt vmcnt(0)" ::: "memory");
        }
        __builtin_amdgcn_s_barrier();
    }

    // ---- final epilogue: bias + f32 scatter ----
    {
        const float* b2e = b2 + (size_t)e * 512;
        float bv2[8];
        #pragma unroll
        for (int j = 0; j < 8; ++j) bv2[j] = b2e[wc * 128 + j * 16 + lrow];
        #pragma unroll
        for (int i = 0; i < 2; ++i)
            #pragma unroll
            for (int q = 0; q < 4; ++q) {
                int row = wr * 32 + i * 16 + kq * 4 + q;
                if (m0 + row < cnt) {
                    float* op = out + (size_t)toks[row] * HID;
                    #pragma unroll
                    for (int j = 0; j < 8; ++j)
                        op[wc * 128 + j * 16 + lrow] = acc[i][j][q] + bv2[j];
                }
            }
    }
    #undef ABUF
    #undef BBUF
    #undef HBUF
}

extern "C" void kernel_launch(void* const* d_in, const int* in_sizes, int n_in,
                              void* d_out, int out_size, void* d_ws, size_t ws_size,
                              hipStream_t stream)
{
    const float* x  = (const float*)d_in[0];
    const float* Wr = (const float*)d_in[1];
    const float* br = (const float*)d_in[2];
    const float* W1 = (const float*)d_in[3];
    const float* b1 = (const float*)d_in[4];
    const float* W2 = (const float*)d_in[5];
    const float* b2 = (const float*)d_in[6];

    float* out     = (float*)d_out;
    float* ids_out = out + (size_t)N_TOK * HID;

    char* ws     = (char*)d_ws;
    int* counts  = (int*)ws;            // 16 ints
    int* offsets = counts + 16;         // 11 used
    int* toff    = counts + 32;         // 11 used
    int* cursors = counts + 48;         // 16
    int* eid     = (int*)(ws + 1024);
    int* perm    = eid + N_TOK;
    short* W1b   = (short*)(ws + 1024 + (size_t)2 * N_TOK * 4);
    short* W2b   = W1b + (size_t)NEXP * 512 * 512;
    short* xb    = W2b + (size_t)NEXP * 512 * 512;

    (void)hipMemsetAsync(d_ws, 0, 1024, stream);
    router_kernel<<<2048, 256, 0, stream>>>(x, Wr, br, eid, ids_out, counts, xb);
    wconvert_kernel<<<dim3(8, 8, 2 * NEXP), 256, 0, stream>>>(W1, W2, W1b, W2b,
                                                              counts, offsets, toff);
    scatter_kernel<<<512, 256, 0, stream>>>(eid, offsets, cursors, perm);

    int ntiles = (N_TOK + 63) / 64 + NEXP;   // upper bound on 64-row tiles (2058)
    expert_fused<<<ntiles, 512, 0, stream>>>(xb, W1b, W2b, b1, b2,
                                             offsets, toff, perm, out);
}